// Round 1
// baseline (1537.303 us; speedup 1.0000x reference)
//
#include <hip/hip_runtime.h>

#define NW 12
#define NL 4

struct Cx { float re, im; };

// ---------------- precompute: cos/sin of params/2 (batch-uniform) ----------------
__global__ void qr_precompute(const float* __restrict__ params, float2* __restrict__ tab) {
    int i = threadIdx.x;
    if (i < NL * NW) {
        float th = 0.5f * params[i];
        tab[i] = make_float2(cosf(th), sinf(th));
    }
}

// ---------------- register-local gates (j bits, compile-time mask) ----------------
template<int M>
__device__ __forceinline__ void ry_local(Cx* st, float c, float s) {
    #pragma unroll
    for (int j0 = 0; j0 < 16; ++j0) {
        if (j0 & M) continue;
        const int j1 = j0 | M;
        Cx a = st[j0], b = st[j1];
        st[j0].re = c * a.re - s * b.re;
        st[j0].im = c * a.im - s * b.im;
        st[j1].re = s * a.re + c * b.re;
        st[j1].im = s * a.im + c * b.im;
    }
}

template<int M>
__device__ __forceinline__ void rx_local(Cx* st, float c, float s) {
    #pragma unroll
    for (int j0 = 0; j0 < 16; ++j0) {
        if (j0 & M) continue;
        const int j1 = j0 | M;
        Cx a = st[j0], b = st[j1];
        // RX = [[c, -i s], [-i s, c]]
        st[j0].re = c * a.re + s * b.im;
        st[j0].im = c * a.im - s * b.re;
        st[j1].re = s * a.im + c * b.re;
        st[j1].im = -s * a.re + c * b.im;
    }
}

template<int M>
__device__ __forceinline__ void rz_local(Cx* st, float c, float s) {
    #pragma unroll
    for (int j = 0; j < 16; ++j) {
        const float si = (j & M) ? s : -s;   // bit0 -> e^{-i th/2}, bit1 -> e^{+i th/2}
        float re = st[j].re, im = st[j].im;
        st[j].re = c * re - si * im;
        st[j].im = c * im + si * re;
    }
}

// ---------------- lane-bit gates (shfl_xor exchange) ----------------
__device__ __forceinline__ void ry_lane(Cx* st, int lm, float c, float s, int lane) {
    const float ss = (lane & lm) ? s : -s;
    #pragma unroll
    for (int j = 0; j < 16; ++j) {
        float pr = __shfl_xor(st[j].re, lm, 64);
        float pi = __shfl_xor(st[j].im, lm, 64);
        st[j].re = c * st[j].re + ss * pr;
        st[j].im = c * st[j].im + ss * pi;
    }
}

__device__ __forceinline__ void rx_lane(Cx* st, int lm, float c, float s) {
    // RX symmetric: new = c*own - i*s*partner  (same formula both sides)
    #pragma unroll
    for (int j = 0; j < 16; ++j) {
        float pr = __shfl_xor(st[j].re, lm, 64);
        float pi = __shfl_xor(st[j].im, lm, 64);
        st[j].re = c * st[j].re + s * pi;
        st[j].im = c * st[j].im - s * pr;
    }
}

// diagonal RZ where the wire bit is thread-uniform (lane or wave bit)
__device__ __forceinline__ void rz_sign(Cx* st, bool hi, float c, float s) {
    const float si = hi ? s : -s;
    #pragma unroll
    for (int j = 0; j < 16; ++j) {
        float re = st[j].re, im = st[j].im;
        st[j].re = c * re - si * im;
        st[j].im = c * im + si * re;
    }
}

// ---------------- cross-wave exchange via LDS (SoA, conflict-free) ----------------
__device__ __forceinline__ void lds_fetch_partner(float* lre, float* lim, Cx* st, Cx* pv,
                                                  int t, int tmask) {
    __syncthreads();
    #pragma unroll
    for (int j = 0; j < 16; ++j) {
        lre[t + 256 * j] = st[j].re;
        lim[t + 256 * j] = st[j].im;
    }
    __syncthreads();
    const int p = t ^ tmask;
    #pragma unroll
    for (int j = 0; j < 16; ++j) {
        pv[j].re = lre[p + 256 * j];
        pv[j].im = lim[p + 256 * j];
    }
}

__device__ __forceinline__ void ry_mix(Cx* st, const Cx* pv, bool hi, float c, float s) {
    const float ss = hi ? s : -s;
    #pragma unroll
    for (int j = 0; j < 16; ++j) {
        st[j].re = c * st[j].re + ss * pv[j].re;
        st[j].im = c * st[j].im + ss * pv[j].im;
    }
}

__device__ __forceinline__ void rx_mix(Cx* st, const Cx* pv, float c, float s) {
    #pragma unroll
    for (int j = 0; j < 16; ++j) {
        st[j].re = c * st[j].re + s * pv[j].im;
        st[j].im = c * st[j].im - s * pv[j].re;
    }
}

// CNOT on two register-local j bits: pure compile-time rename
template<int CM, int TM>
__device__ __forceinline__ void cnot_local(Cx* st) {
    #pragma unroll
    for (int j = 0; j < 16; ++j) {
        if ((j & CM) && !(j & TM)) {
            Cx tmp = st[j]; st[j] = st[j | TM]; st[j | TM] = tmp;
        }
    }
}

// ---------------- main kernel: one block = one sample ----------------
__global__ __launch_bounds__(256) void qr_main(
        const float* __restrict__ inputs,
        const float2* __restrict__ tab,
        const float* __restrict__ head_w,
        const float* __restrict__ head_b,
        float* __restrict__ out)
{
    __shared__ float lre[4096];
    __shared__ float lim[4096];

    const int t = threadIdx.x;      // 0..255; state index s = t*16 + j
    const int lane = t & 63;
    const int b = blockIdx.x;

    Cx st[16];
    #pragma unroll
    for (int j = 0; j < 16; ++j) { st[j].re = 0.0f; st[j].im = 0.0f; }
    if (t == 0) st[0].re = 1.0f;

    // per-sample encoding angles
    float cy[NW], sy[NW];
    #pragma unroll
    for (int i = 0; i < NW; ++i) {
        __sincosf(0.5f * inputs[b * NW + i], &sy[i], &cy[i]);
    }

    Cx pv[16];

    // ---- RY encoding (wire i <-> state bit 11-i) ----
    lds_fetch_partner(lre, lim, st, pv, t, 128);              // wire 0 (t bit7)
    ry_mix(st, pv, (t & 128) != 0, cy[0], sy[0]);
    lds_fetch_partner(lre, lim, st, pv, t, 64);               // wire 1 (t bit6)
    ry_mix(st, pv, (t & 64) != 0, cy[1], sy[1]);
    #pragma unroll 1
    for (int i = 2; i <= 7; ++i) {                            // wires 2..7 (lane bits 5..0)
        ry_lane(st, 1 << (7 - i), cy[i], sy[i], lane);
    }
    ry_local<8>(st, cy[8], sy[8]);                            // wires 8..11 (j bits 3..0)
    ry_local<4>(st, cy[9], sy[9]);
    ry_local<2>(st, cy[10], sy[10]);
    ry_local<1>(st, cy[11], sy[11]);

    // ---- layers ----
    #pragma unroll 1
    for (int l = 0; l < NL; ++l) {
        const float2* tl = tab + l * NW;
        {   // wire 0
            float2 cs = tl[0];
            lds_fetch_partner(lre, lim, st, pv, t, 128);
            rx_mix(st, pv, cs.x, cs.y);
            rz_sign(st, (t & 128) != 0, cs.x, cs.y);
        }
        {   // wire 1
            float2 cs = tl[1];
            lds_fetch_partner(lre, lim, st, pv, t, 64);
            rx_mix(st, pv, cs.x, cs.y);
            rz_sign(st, (t & 64) != 0, cs.x, cs.y);
        }
        #pragma unroll 1
        for (int i = 2; i <= 7; ++i) {                        // wires 2..7
            float2 cs = tl[i];
            int lm = 1 << (7 - i);
            rx_lane(st, lm, cs.x, cs.y);
            rz_sign(st, (lane & lm) != 0, cs.x, cs.y);
        }
        { float2 cs = tl[8];  rx_local<8>(st, cs.x, cs.y); rz_local<8>(st, cs.x, cs.y); }
        { float2 cs = tl[9];  rx_local<4>(st, cs.x, cs.y); rz_local<4>(st, cs.x, cs.y); }
        { float2 cs = tl[10]; rx_local<2>(st, cs.x, cs.y); rz_local<2>(st, cs.x, cs.y); }
        { float2 cs = tl[11]; rx_local<1>(st, cs.x, cs.y); rz_local<1>(st, cs.x, cs.y); }

        // ---- CNOT chain ----
        // CNOT(0,1): control t bit7, target t bit6 -> swap waves 2<->3 via LDS
        __syncthreads();
        #pragma unroll
        for (int j = 0; j < 16; ++j) {
            lre[t + 256 * j] = st[j].re;
            lim[t + 256 * j] = st[j].im;
        }
        __syncthreads();
        if (t & 128) {
            const int p = t ^ 64;
            #pragma unroll
            for (int j = 0; j < 16; ++j) {
                st[j].re = lre[p + 256 * j];
                st[j].im = lim[p + 256 * j];
            }
        }
        // CNOT(1,2): control t bit6 (wave-uniform), target lane bit5
        if (t & 64) {
            #pragma unroll
            for (int j = 0; j < 16; ++j) {
                st[j].re = __shfl_xor(st[j].re, 32, 64);
                st[j].im = __shfl_xor(st[j].im, 32, 64);
            }
        }
        // CNOT(2,3)..(6,7): control lane bit cbit, target lane bit cbit-1
        #pragma unroll 1
        for (int cbit = 5; cbit >= 1; --cbit) {
            int cm = 1 << cbit;
            int tm = 1 << (cbit - 1);
            int src = (lane & cm) ? (lane ^ tm) : lane;
            #pragma unroll
            for (int j = 0; j < 16; ++j) {
                st[j].re = __shfl(st[j].re, src, 64);
                st[j].im = __shfl(st[j].im, src, 64);
            }
        }
        // CNOT(7,8): control lane bit0, target j bit3 (per-lane predicated swap)
        if (lane & 1) {
            #pragma unroll
            for (int j = 0; j < 8; ++j) {
                Cx tmp = st[j]; st[j] = st[j | 8]; st[j | 8] = tmp;
            }
        }
        // CNOT(8,9),(9,10),(10,11): register renames (free)
        cnot_local<8, 4>(st);
        cnot_local<4, 2>(st);
        cnot_local<2, 1>(st);
    }

    // ---- measurement: phi_t = sum_j (coeffA(t) + coeffB(j)) * |st[j]|^2 ----
    float p[16];
    #pragma unroll
    for (int j = 0; j < 16; ++j)
        p[j] = st[j].re * st[j].re + st[j].im * st[j].im;

    float w[NW];
    #pragma unroll
    for (int i = 0; i < NW; ++i) w[i] = head_w[i];

    float coeffA = 0.0f;
    #pragma unroll
    for (int i = 0; i < 8; ++i)                 // wires 0..7 live on thread bits 7..0
        coeffA += ((t >> (7 - i)) & 1) ? -w[i] : w[i];

    float phi = 0.0f;
    #pragma unroll
    for (int j = 0; j < 16; ++j) {
        float cj = coeffA;
        cj += (j & 8) ? -w[8]  : w[8];          // wire 8  = j bit3
        cj += (j & 4) ? -w[9]  : w[9];
        cj += (j & 2) ? -w[10] : w[10];
        cj += (j & 1) ? -w[11] : w[11];
        phi += cj * p[j];
    }

    #pragma unroll
    for (int m = 32; m >= 1; m >>= 1)
        phi += __shfl_xor(phi, m, 64);

    __syncthreads();
    if (lane == 0) lre[t >> 6] = phi;
    __syncthreads();
    if (t == 0)
        out[b] = lre[0] + lre[1] + lre[2] + lre[3] + head_b[0];
}

extern "C" void kernel_launch(void* const* d_in, const int* in_sizes, int n_in,
                              void* d_out, int out_size, void* d_ws, size_t ws_size,
                              hipStream_t stream) {
    const float* inputs = (const float*)d_in[0];
    const float* params = (const float*)d_in[1];
    const float* head_w = (const float*)d_in[2];
    const float* head_b = (const float*)d_in[3];
    float* out = (float*)d_out;
    float2* tab = (float2*)d_ws;   // 48 * 8B = 384B

    const int batch = in_sizes[0] / NW;

    qr_precompute<<<1, 64, 0, stream>>>(params, tab);
    qr_main<<<batch, 256, 0, stream>>>(inputs, tab, head_w, head_b, out);
}

// Round 2
// 1229.760 us; speedup vs baseline: 1.2501x; 1.2501x over previous
//
#include <hip/hip_runtime.h>

#define NW 12

struct Cx { float re, im; };

// data-movement source index for the 5-CNOT chain on 6 local bits
// (control bit k+1, target bit k, applied from high control to low)
__device__ constexpr int perm64c(int j) {
    j ^= (j >> 1) & 1;
    j ^= (j >> 1) & 2;
    j ^= (j >> 1) & 4;
    j ^= (j >> 1) & 8;
    j ^= (j >> 1) & 16;
    return j;
}

// parity of j bits 5..(5-k)  (prefix parity, compile-time after unroll)
__device__ constexpr int ppar(int j, int k) {
    int p = 0;
    for (int i = 0; i <= k; ++i) p ^= (j >> (5 - i)) & 1;
    return p;
}

// ---------------- RX butterfly on local bit M ----------------
template<int M>
__device__ __forceinline__ void rx_m(Cx st[64], float c, float s) {
    #pragma unroll
    for (int j0 = 0; j0 < 64; ++j0) {
        if (j0 & M) continue;
        const int j1 = j0 | M;
        const float ar = st[j0].re, ai = st[j0].im;
        const float br = st[j1].re, bi = st[j1].im;
        st[j0].re = c * ar + s * bi;
        st[j0].im = c * ai - s * br;
        st[j1].re = c * br + s * ai;
        st[j1].im = c * bi - s * ar;
    }
}

// 6 RX gates on the local bits; wire k of active set <-> mask 32>>k
__device__ __forceinline__ void rx_sweep(Cx st[64], const float2* __restrict__ cs) {
    { const float2 q = cs[0]; rx_m<32>(st, q.x, q.y); }
    { const float2 q = cs[1]; rx_m<16>(st, q.x, q.y); }
    { const float2 q = cs[2]; rx_m<8>(st, q.x, q.y); }
    { const float2 q = cs[3]; rx_m<4>(st, q.x, q.y); }
    { const float2 q = cs[4]; rx_m<2>(st, q.x, q.y); }
    { const float2 q = cs[5]; rx_m<1>(st, q.x, q.y); }
}

// combined diagonal (6 RZs of the local wires) via precomputed table
__device__ __forceinline__ void diag_apply(Cx st[64], const float2* __restrict__ z) {
    #pragma unroll
    for (int j = 0; j < 64; ++j) {
        const float2 zz = z[j];
        const float re = st[j].re, im = st[j].im;
        st[j].re = re * zz.x - im * zz.y;
        st[j].im = im * zz.x + re * zz.y;
    }
}

// compile-time permutation (register renames)
__device__ __forceinline__ void perm_apply(Cx st[64]) {
    Cx tmp[64];
    #pragma unroll
    for (int j = 0; j < 64; ++j) tmp[j] = st[perm64c(j)];
    #pragma unroll
    for (int j = 0; j < 64; ++j) st[j] = tmp[j];
}

// CNOT(5,6) when wire5 = local bit0, wire6 = lane bit5 (L2 layout)
__device__ __forceinline__ void cnot56_L2(Cx st[64]) {
    #pragma unroll
    for (int j = 1; j < 64; j += 2) {
        st[j].re = __shfl_xor(st[j].re, 32, 64);
        st[j].im = __shfl_xor(st[j].im, 32, 64);
    }
}

// CNOT(5,6) when wire5 = lane bit0, wire6 = local bit5 (L1 layout)
__device__ __forceinline__ void cnot56_L1(Cx st[64], int lane) {
    const bool c = (lane & 1) != 0;
    #pragma unroll
    for (int j = 0; j < 32; ++j) {
        const float ar = st[j].re, ai = st[j].im;
        const float br = st[j + 32].re, bi = st[j + 32].im;
        st[j].re      = c ? br : ar;  st[j].im      = c ? bi : ai;
        st[j + 32].re = c ? ar : br;  st[j + 32].im = c ? ai : bi;
    }
}

// ---------------- in-wave 64x64 transpose via LDS (no barriers) ----------------
// logical (row R, col C) stored at byte R*256 + (((C>>2) ^ (R&15))<<4) + (C&3)*4
template<bool PRE, bool POST>
__device__ __forceinline__ void tpose(float* pl, Cx st[64], const int lane, const int* A16) {
    char* base = reinterpret_cast<char*>(pl);
    const int ls = lane & 15;
    const int wb = lane << 8;
    // ---- RE plane ----
    #pragma unroll
    for (int g = 0; g < 16; ++g) {
        float4 v;
        v.x = st[PRE ? perm64c(4 * g + 0) : 4 * g + 0].re;
        v.y = st[PRE ? perm64c(4 * g + 1) : 4 * g + 1].re;
        v.z = st[PRE ? perm64c(4 * g + 2) : 4 * g + 2].re;
        v.w = st[PRE ? perm64c(4 * g + 3) : 4 * g + 3].re;
        *reinterpret_cast<float4*>(base + wb + ((g ^ ls) << 4)) = v;
    }
    #pragma unroll
    for (int j = 0; j < 64; ++j) {
        const int r = POST ? perm64c(j) : j;
        st[j].re = *reinterpret_cast<const float*>(base + A16[r & 15] + (r << 8));
    }
    // ---- IM plane (reuses buffer; per-wave DS ordering guarantees WAR safety) ----
    #pragma unroll
    for (int g = 0; g < 16; ++g) {
        float4 v;
        v.x = st[PRE ? perm64c(4 * g + 0) : 4 * g + 0].im;
        v.y = st[PRE ? perm64c(4 * g + 1) : 4 * g + 1].im;
        v.z = st[PRE ? perm64c(4 * g + 2) : 4 * g + 2].im;
        v.w = st[PRE ? perm64c(4 * g + 3) : 4 * g + 3].im;
        *reinterpret_cast<float4*>(base + wb + ((g ^ ls) << 4)) = v;
    }
    #pragma unroll
    for (int j = 0; j < 64; ++j) {
        const int r = POST ? perm64c(j) : j;
        st[j].im = *reinterpret_cast<const float*>(base + A16[r & 15] + (r << 8));
    }
}

// ---------------- precompute (batch-uniform gate constants) ----------------
__global__ void qr_pre(const float* __restrict__ params,
                       float2* __restrict__ tabcs,   // [8][6]
                       float2* __restrict__ zdiag)   // [6][64]
{
    const int t = threadIdx.x;
    if (t < 48) {
        const int h = t / 6, k = t - h * 6;
        const int l = h >> 1;
        const int base = (((h & 3) == 0) || ((h & 3) == 3)) ? 6 : 0;
        const float th = 0.5f * params[l * 12 + base + k];
        tabcs[t] = make_float2(cosf(th), sinf(th));
    }
    if (t < 384) {
        const int h = t >> 6, j = t & 63;
        const int l = h >> 1;
        const int base = (((h & 3) == 0) || ((h & 3) == 3)) ? 6 : 0;
        float pr = 1.f, pi = 0.f;
        for (int k = 0; k < 6; ++k) {
            const float th = 0.5f * params[l * 12 + base + k];
            const float c = cosf(th), s = sinf(th);
            const float ss = (j & (32 >> k)) ? s : -s;   // bit set -> e^{+i th/2}
            const float nr = pr * c - pi * ss;
            pi = pr * ss + pi * c;
            pr = nr;
        }
        zdiag[t] = make_float2(pr, pi);
    }
}

// ---------------- main: one wave = one sample ----------------
__global__ __launch_bounds__(64, 2) void qr_main(
    const float* __restrict__ inputs,
    const float2* __restrict__ tabcs,
    const float2* __restrict__ zdiag,
    const float* __restrict__ head_w,
    const float* __restrict__ head_b,
    float* __restrict__ out)
{
    __shared__ __align__(16) float pl[4096];   // 16 KiB transpose buffer
    const int lane = threadIdx.x;
    const int b = blockIdx.x;

    // per-sample encoding angles
    float cy[12], sy[12];
    #pragma unroll
    for (int i = 0; i < 12; ++i) {
        __sincosf(0.5f * inputs[b * 12 + i], &sy[i], &cy[i]);
    }

    // product-state init in L1 (lane bits = wires 0-5, local bits = wires 6-11)
    float F = 1.f;
    #pragma unroll
    for (int i = 0; i < 6; ++i) F *= (lane & (32 >> i)) ? sy[i] : cy[i];

    float t2[2], t4[4], t8[8], t16[16], t32[32];
    t2[0] = cy[6]; t2[1] = sy[6];
    #pragma unroll
    for (int m = 0; m < 4; ++m)  t4[m]  = t2[m >> 1]  * ((m & 1) ? sy[7]  : cy[7]);
    #pragma unroll
    for (int m = 0; m < 8; ++m)  t8[m]  = t4[m >> 1]  * ((m & 1) ? sy[8]  : cy[8]);
    #pragma unroll
    for (int m = 0; m < 16; ++m) t16[m] = t8[m >> 1]  * ((m & 1) ? sy[9]  : cy[9]);
    #pragma unroll
    for (int m = 0; m < 32; ++m) t32[m] = t16[m >> 1] * ((m & 1) ? sy[10] : cy[10]);

    Cx st[64];
    #pragma unroll
    for (int j = 0; j < 64; ++j) {
        st[j].re = F * t32[j >> 1] * ((j & 1) ? sy[11] : cy[11]);
        st[j].im = 0.f;
    }

    // cached transpose read-address bases (bytes), 16 distinct values
    int A16[16];
    #pragma unroll
    for (int m = 0; m < 16; ++m)
        A16[m] = ((((lane >> 2) ^ m) << 4) | ((lane & 3) << 2));

    // 8 half-layers; layout alternates L1/L2 via transposes
    #pragma unroll 1
    for (int h = 0; h < 8; ++h) {
        rx_sweep(st, tabcs + h * 6);
        if (h < 6) diag_apply(st, zdiag + (h << 6));

        if (h == 1 || h == 5) {
            perm_apply(st);          // CNOT(0,1)..(4,5) renames (L2)
            cnot56_L2(st);           // CNOT(5,6); chain(6..11) deferred
        } else if (h == 3) {
            cnot56_L1(st, lane);     // CNOT(5,6) in L1
            perm_apply(st);          // CNOT(6,7)..(10,11) renames (L1)
        } else if (h == 0 || h == 4) {
            tpose<false, false>(pl, st, lane, A16);
        } else if (h == 2) {
            tpose<true, true>(pl, st, lane, A16);   // pre: this layer's (0,1)..(4,5); post: deferred chain
        } else if (h == 6) {
            tpose<false, true>(pl, st, lane, A16);  // post: layer-2's deferred chain
        }
        // h == 7: done (layer-3 RZs + CNOT chain folded into measurement)
    }

    // measurement in L1; layer-3 CNOT chain -> prefix-parity signs
    float w[12];
    #pragma unroll
    for (int i = 0; i < 12; ++i) w[i] = head_w[i];

    float C = 0.f; int par = 0;
    #pragma unroll
    for (int i = 0; i < 6; ++i) {
        par ^= (lane >> (5 - i)) & 1;
        C += par ? -w[i] : w[i];
    }
    const float sg = par ? -1.f : 1.f;

    float phi = 0.f;
    #pragma unroll
    for (int j = 0; j < 64; ++j) {
        const float p = st[j].re * st[j].re + st[j].im * st[j].im;
        float D = 0.f;
        #pragma unroll
        for (int k = 0; k < 6; ++k) {
            D += ppar(j, k) ? -w[6 + k] : w[6 + k];
        }
        phi += (C + sg * D) * p;
    }

    #pragma unroll
    for (int m = 32; m; m >>= 1) phi += __shfl_xor(phi, m, 64);
    if (lane == 0) out[b] = phi + head_b[0];
}

extern "C" void kernel_launch(void* const* d_in, const int* in_sizes, int n_in,
                              void* d_out, int out_size, void* d_ws, size_t ws_size,
                              hipStream_t stream) {
    const float* inputs = (const float*)d_in[0];
    const float* params = (const float*)d_in[1];
    const float* head_w = (const float*)d_in[2];
    const float* head_b = (const float*)d_in[3];
    float* out = (float*)d_out;

    float2* tabcs = (float2*)d_ws;       // 48 float2
    float2* zdiag = tabcs + 48;          // 384 float2

    const int batch = in_sizes[0] / NW;

    qr_pre<<<1, 384, 0, stream>>>(params, tabcs, zdiag);
    qr_main<<<batch, 64, 0, stream>>>(inputs, tabcs, zdiag, head_w, head_b, out);
}

// Round 5
// 675.878 us; speedup vs baseline: 2.2745x; 1.8195x over previous
//
#include <hip/hip_runtime.h>

#define NW 12

struct Cx { float re, im; };

// data-movement source index for the 5-CNOT chain on 6 local bits
// (control bit k+1, target bit k, applied from high control to low)
__device__ constexpr int perm64c(int j) {
    j ^= (j >> 1) & 1;
    j ^= (j >> 1) & 2;
    j ^= (j >> 1) & 4;
    j ^= (j >> 1) & 8;
    j ^= (j >> 1) & 16;
    return j;
}

// parity of j bits 5..(5-k)  (prefix parity, compile-time after unroll)
__device__ constexpr int ppar(int j, int k) {
    int p = 0;
    for (int i = 0; i <= k; ++i) p ^= (j >> (5 - i)) & 1;
    return p;
}

// ---------------- RX butterfly on local bit M ----------------
template<int M>
__device__ __forceinline__ void rx_m(Cx st[64], float c, float s) {
    #pragma unroll
    for (int j0 = 0; j0 < 64; ++j0) {
        if (j0 & M) continue;
        const int j1 = j0 | M;
        const float ar = st[j0].re, ai = st[j0].im;
        const float br = st[j1].re, bi = st[j1].im;
        st[j0].re = c * ar + s * bi;
        st[j0].im = c * ai - s * br;
        st[j1].re = c * br + s * ai;
        st[j1].im = c * bi - s * ar;
    }
}

// 6 RX gates on the local bits; wire k of active set <-> mask 32>>k
__device__ __forceinline__ void rx_sweep(Cx st[64], const float2* __restrict__ cs) {
    { const float2 q = cs[0]; rx_m<32>(st, q.x, q.y); }
    { const float2 q = cs[1]; rx_m<16>(st, q.x, q.y); }
    { const float2 q = cs[2]; rx_m<8>(st, q.x, q.y); }
    { const float2 q = cs[3]; rx_m<4>(st, q.x, q.y); }
    { const float2 q = cs[4]; rx_m<2>(st, q.x, q.y); }
    { const float2 q = cs[5]; rx_m<1>(st, q.x, q.y); }
}

// combined diagonal (6 RZs of the local wires) via precomputed table
__device__ __forceinline__ void diag_apply(Cx st[64], const float2* __restrict__ z) {
    #pragma unroll
    for (int j = 0; j < 64; ++j) {
        const float2 zz = z[j];
        const float re = st[j].re, im = st[j].im;
        st[j].re = re * zz.x - im * zz.y;
        st[j].im = im * zz.x + re * zz.y;
    }
}

// compile-time permutation (register renames)
__device__ __forceinline__ void perm_apply(Cx st[64]) {
    Cx tmp[64];
    #pragma unroll
    for (int j = 0; j < 64; ++j) tmp[j] = st[perm64c(j)];
    #pragma unroll
    for (int j = 0; j < 64; ++j) st[j] = tmp[j];
}

// CNOT(5,6) when wire5 = local bit0, wire6 = lane bit5 (L2 layout)
__device__ __forceinline__ void cnot56_L2(Cx st[64]) {
    #pragma unroll
    for (int j = 1; j < 64; j += 2) {
        st[j].re = __shfl_xor(st[j].re, 32, 64);
        st[j].im = __shfl_xor(st[j].im, 32, 64);
    }
}

// CNOT(5,6) when wire5 = lane bit0, wire6 = local bit5 (L1 layout)
__device__ __forceinline__ void cnot56_L1(Cx st[64], int lane) {
    const bool c = (lane & 1) != 0;
    #pragma unroll
    for (int j = 0; j < 32; ++j) {
        const float ar = st[j].re, ai = st[j].im;
        const float br = st[j + 32].re, bi = st[j + 32].im;
        st[j].re      = c ? br : ar;  st[j].im      = c ? bi : ai;
        st[j + 32].re = c ? ar : br;  st[j + 32].im = c ? ai : bi;
    }
}

// ---------------- in-wave 64x64 transpose via LDS (no barriers) ----------------
// logical (row R, col C) stored at byte R*256 + (((C>>2) ^ (R&15))<<4) + (C&3)*4
template<bool PRE, bool POST>
__device__ __forceinline__ void tpose(float* pl, Cx st[64], const int lane, const int* A16) {
    char* base = reinterpret_cast<char*>(pl);
    const int ls = lane & 15;
    const int wb = lane << 8;
    // ---- RE plane ----
    #pragma unroll
    for (int g = 0; g < 16; ++g) {
        float4 v;
        v.x = st[PRE ? perm64c(4 * g + 0) : 4 * g + 0].re;
        v.y = st[PRE ? perm64c(4 * g + 1) : 4 * g + 1].re;
        v.z = st[PRE ? perm64c(4 * g + 2) : 4 * g + 2].re;
        v.w = st[PRE ? perm64c(4 * g + 3) : 4 * g + 3].re;
        *reinterpret_cast<float4*>(base + wb + ((g ^ ls) << 4)) = v;
    }
    #pragma unroll
    for (int j = 0; j < 64; ++j) {
        const int r = POST ? perm64c(j) : j;
        st[j].re = *reinterpret_cast<const float*>(base + A16[r & 15] + (r << 8));
    }
    // ---- IM plane (reuses buffer; per-wave DS ordering guarantees WAR safety) ----
    #pragma unroll
    for (int g = 0; g < 16; ++g) {
        float4 v;
        v.x = st[PRE ? perm64c(4 * g + 0) : 4 * g + 0].im;
        v.y = st[PRE ? perm64c(4 * g + 1) : 4 * g + 1].im;
        v.z = st[PRE ? perm64c(4 * g + 2) : 4 * g + 2].im;
        v.w = st[PRE ? perm64c(4 * g + 3) : 4 * g + 3].im;
        *reinterpret_cast<float4*>(base + wb + ((g ^ ls) << 4)) = v;
    }
    #pragma unroll
    for (int j = 0; j < 64; ++j) {
        const int r = POST ? perm64c(j) : j;
        st[j].im = *reinterpret_cast<const float*>(base + A16[r & 15] + (r << 8));
    }
}

// ---------------- precompute (batch-uniform gate constants) ----------------
__global__ void qr_pre(const float* __restrict__ params,
                       float2* __restrict__ tabcs,   // [8][6]
                       float2* __restrict__ zdiag)   // [6][64]
{
    const int t = threadIdx.x;
    if (t < 48) {
        const int h = t / 6, k = t - h * 6;
        const int l = h >> 1;
        const int base = (((h & 3) == 0) || ((h & 3) == 3)) ? 6 : 0;
        const float th = 0.5f * params[l * 12 + base + k];
        tabcs[t] = make_float2(cosf(th), sinf(th));
    }
    if (t < 384) {
        const int h = t >> 6, j = t & 63;
        const int l = h >> 1;
        const int base = (((h & 3) == 0) || ((h & 3) == 3)) ? 6 : 0;
        float pr = 1.f, pi = 0.f;
        for (int k = 0; k < 6; ++k) {
            const float th = 0.5f * params[l * 12 + base + k];
            const float c = cosf(th), s = sinf(th);
            const float ss = (j & (32 >> k)) ? s : -s;   // bit set -> e^{+i th/2}
            const float nr = pr * c - pi * ss;
            pi = pr * ss + pi * c;
            pr = nr;
        }
        zdiag[t] = make_float2(pr, pi);
    }
}

// ---------------- main: one wave = one sample ----------------
// launch_bounds(64, 1): 1 wave/EU minimum -> VGPR cap 512. Round-2's (64,2)
// capped at 256 and the allocator settled at 128 + scratch (4.2 GB HBM spill
// traffic, 42% of peak). State alone is 128 VGPRs; it must live in registers.
__global__ __launch_bounds__(64, 1) void qr_main(
    const float* __restrict__ inputs,
    const float2* __restrict__ tabcs,
    const float2* __restrict__ zdiag,
    const float* __restrict__ head_w,
    const float* __restrict__ head_b,
    float* __restrict__ out)
{
    __shared__ __align__(16) float pl[4096];   // 16 KiB transpose buffer
    const int lane = threadIdx.x;
    const int b = blockIdx.x;

    // per-sample encoding angles
    float cy[12], sy[12];
    #pragma unroll
    for (int i = 0; i < 12; ++i) {
        __sincosf(0.5f * inputs[b * 12 + i], &sy[i], &cy[i]);
    }

    // product-state init in L1 (lane bits = wires 0-5, local bits = wires 6-11)
    float F = 1.f;
    #pragma unroll
    for (int i = 0; i < 6; ++i) F *= (lane & (32 >> i)) ? sy[i] : cy[i];

    // low transient pressure: two 8-entry product tables (16 regs, not 62)
    float hi[8], lo[8];
    #pragma unroll
    for (int m = 0; m < 8; ++m) {
        hi[m] = ((m & 4) ? sy[6] : cy[6]) * ((m & 2) ? sy[7]  : cy[7])  * ((m & 1) ? sy[8]  : cy[8]);
        lo[m] = ((m & 4) ? sy[9] : cy[9]) * ((m & 2) ? sy[10] : cy[10]) * ((m & 1) ? sy[11] : cy[11]);
    }

    Cx st[64];
    #pragma unroll
    for (int j = 0; j < 64; ++j) {
        st[j].re = F * hi[j >> 3] * lo[j & 7];
        st[j].im = 0.f;
    }

    // cached transpose read-address bases (bytes), 16 distinct values
    int A16[16];
    #pragma unroll
    for (int m = 0; m < 16; ++m)
        A16[m] = ((((lane >> 2) ^ m) << 4) | ((lane & 3) << 2));

    // 8 half-layers; layout alternates L1/L2 via transposes
    #pragma unroll 1
    for (int h = 0; h < 8; ++h) {
        rx_sweep(st, tabcs + h * 6);
        if (h < 6) diag_apply(st, zdiag + (h << 6));

        if (h == 1 || h == 5) {
            perm_apply(st);          // CNOT(0,1)..(4,5) renames (L2)
            cnot56_L2(st);           // CNOT(5,6); chain(6..11) deferred
        } else if (h == 3) {
            cnot56_L1(st, lane);     // CNOT(5,6) in L1
            perm_apply(st);          // CNOT(6,7)..(10,11) renames (L1)
        } else if (h == 0 || h == 4) {
            tpose<false, false>(pl, st, lane, A16);
        } else if (h == 2) {
            tpose<true, true>(pl, st, lane, A16);   // pre: this layer's (0,1)..(4,5); post: deferred chain
        } else if (h == 6) {
            tpose<false, true>(pl, st, lane, A16);  // post: layer-2's deferred chain
        }
        // h == 7: done (layer-3 RZs + CNOT chain folded into measurement)
    }

    // measurement in L1; layer-3 CNOT chain -> prefix-parity signs
    float w[12];
    #pragma unroll
    for (int i = 0; i < 12; ++i) w[i] = head_w[i];

    float C = 0.f; int par = 0;
    #pragma unroll
    for (int i = 0; i < 6; ++i) {
        par ^= (lane >> (5 - i)) & 1;
        C += par ? -w[i] : w[i];
    }
    const float sg = par ? -1.f : 1.f;

    float phi = 0.f;
    #pragma unroll
    for (int j = 0; j < 64; ++j) {
        const float p = st[j].re * st[j].re + st[j].im * st[j].im;
        float D = 0.f;
        #pragma unroll
        for (int k = 0; k < 6; ++k) {
            D += ppar(j, k) ? -w[6 + k] : w[6 + k];
        }
        phi += (C + sg * D) * p;
    }

    #pragma unroll
    for (int m = 32; m; m >>= 1) phi += __shfl_xor(phi, m, 64);
    if (lane == 0) out[b] = phi + head_b[0];
}

extern "C" void kernel_launch(void* const* d_in, const int* in_sizes, int n_in,
                              void* d_out, int out_size, void* d_ws, size_t ws_size,
                              hipStream_t stream) {
    const float* inputs = (const float*)d_in[0];
    const float* params = (const float*)d_in[1];
    const float* head_w = (const float*)d_in[2];
    const float* head_b = (const float*)d_in[3];
    float* out = (float*)d_out;

    float2* tabcs = (float2*)d_ws;       // 48 float2
    float2* zdiag = tabcs + 48;          // 384 float2

    const int batch = in_sizes[0] / NW;

    qr_pre<<<1, 384, 0, stream>>>(params, tabcs, zdiag);
    qr_main<<<batch, 64, 0, stream>>>(inputs, tabcs, zdiag, head_w, head_b, out);
}